// Round 1
// baseline (27.219 us; speedup 1.0000x reference)
//
#include <hip/hip_runtime.h>

// REM generator: out[h][i][j], 8 x 2048 x 2048 f32.
// Uniform per-head form: d = i - j;
//   v = (d >= 0 && d % n == 0) ? F[Lc(d)] * G[Lc(d/n)] : 0;  if (d==0) v -= 1;
// where Lc(x) = x if x <= 200 else 0 (the CAP rule maps to exponent 0, value 1).

#define CAP  200
#define ROWS 8     // rows per block

__device__ __forceinline__ float ipow_f(float base, int L) {
    // sign-correct integer power (matches _ipow): |base|^L with sign for odd L, neg base
    float mag = powf(fabsf(base), (float)L);
    float sgn = ((L & 1) && (base < 0.0f)) ? -1.0f : 1.0f;
    return sgn * mag;
}

__global__ __launch_bounds__(256) void rem_kernel(
    const float* __restrict__ eta,
    const float* __restrict__ nu,
    const float* __restrict__ theta,
    float* __restrict__ out)
{
    __shared__ float F[256];
    __shared__ float G[256];

    const int h    = blockIdx.y;
    const int row0 = blockIdx.x * ROWS;
    const int tid  = threadIdx.x;

    // Build per-head tables F[k], G[k] for k = 0..200 (one lane each).
    if (tid <= CAP) {
        const int t = tid;
        float f = 1.0f, g = 1.0f;
        switch (h) {
            case 0: f = ipow_f(tanhf(eta[0]), t); break;                       // lam0^k
            case 1: f = ipow_f(tanhf(eta[1]), t); break;                       // lam1^k
            case 2: g = ipow_f(tanhf(eta[2]), t); break;                       // dilated(4) lam2^k
            case 3: { float gm = 1.0f/(1.0f+expf(-nu[0]));
                      f = ipow_f(gm, t) * cosf(theta[0]*(float)t); } break;    // gam0^k cos
            case 4: { float gm = 1.0f/(1.0f+expf(-nu[1]));
                      f = ipow_f(gm, t) * cosf(theta[1]*(float)t); } break;    // gam1^k cos
            case 5: { float gm = 1.0f/(1.0f+expf(-nu[2]));
                      f = ipow_f(gm, t) * sinf(theta[2]*(float)t); } break;    // gam2^k sin
            case 6: f = cosf(theta[3]*(float)t); g = f; break;                 // dil(3) cos * cos
            case 7: f = sinf(theta[4]*(float)t); g = f; break;                 // dil(2) sin * sin
        }
        F[t] = f; G[t] = g;
    }
    __syncthreads();

    // dilation factor n and magic for d/n (valid for d < 32768, n in {1,2,3,4})
    const int      n_tab[8]   = {1,1,4,1,1,1,3,2};
    const unsigned mag_tab[8] = {65536u,65536u,16384u,65536u,65536u,65536u,21846u,32768u};
    const int      n   = n_tab[h];
    const unsigned mag = mag_tab[h];

    float4* out4 = reinterpret_cast<float4*>(out) + (size_t)h * (2048u * 512u);

    #pragma unroll
    for (int k = 0; k < (ROWS * 512) / 256; ++k) {
        int f4 = tid + k * 256;       // float4 index within block tile
        int r  = f4 >> 9;             // 0..ROWS-1
        int c4 = f4 & 511;            // float4 column
        int i  = row0 + r;
        int j  = c4 << 2;

        float vv[4];
        #pragma unroll
        for (int e = 0; e < 4; ++e) {
            int dd = i - (j + e);
            float val = 0.0f;
            if (dd >= 0) {
                unsigned q   = ((unsigned)dd * mag) >> 16;  // dd / n
                int      rem = dd - (int)(q * (unsigned)n); // dd % n
                if (rem == 0) {
                    int L  = (dd      <= CAP) ? dd      : 0;
                    int Lq = ((int)q  <= CAP) ? (int)q  : 0;
                    val = F[L] * G[Lq];
                }
                if (dd == 0) val -= 1.0f;   // - eye
            }
            vv[e] = val;
        }
        out4[(size_t)i * 512 + c4] = make_float4(vv[0], vv[1], vv[2], vv[3]);
    }
}

extern "C" void kernel_launch(void* const* d_in, const int* in_sizes, int n_in,
                              void* d_out, int out_size, void* d_ws, size_t ws_size,
                              hipStream_t stream) {
    (void)in_sizes; (void)n_in; (void)d_ws; (void)ws_size; (void)out_size;
    const float* eta   = (const float*)d_in[0];
    const float* nu    = (const float*)d_in[1];
    const float* theta = (const float*)d_in[2];
    float* out = (float*)d_out;

    dim3 grid(2048 / ROWS, 8, 1);   // 256 row-groups x 8 heads = 2048 blocks
    rem_kernel<<<grid, 256, 0, stream>>>(eta, nu, theta, out);
}